// Round 9
// baseline (2990.942 us; speedup 1.0000x reference)
//
#include <hip/hip_runtime.h>
#include <stdint.h>

// Fused GIN layer: edge-streamed gather (ds_add_f32 into LDS z; every wave
// streams ALL edges, owns a 64-dim slice) -> convert -> GEMM1^T -> t(LDS)
// -> GEMM2 -> LDS-staged coalesced epilogue. 628 blocks x 4 waves.
#define NN    20000
#define NE    320000
#define MPAD  20096      // 628 * 32
#define NBLK  628
#define DD    256
#define DOUT  128
#define BCAP  1024       // max edges per 32-node block (mean 512)
#define RS    40         // As row stride (elems) within a 32-K slice
#define SS    1288       // As slice stride: 32*40 + 8 pad
#define RSF   258        // zf (f32) row stride
#define STS   264        // epilogue u16 staging row stride
#define SFS   132        // epilogue f32 staging row stride

typedef unsigned short u16;
typedef __attribute__((ext_vector_type(8))) __bf16 bf16x8;
typedef __attribute__((ext_vector_type(4))) float  f32x4;

__device__ __forceinline__ uint32_t f2b(float f){
  union { float f; uint32_t u; } x; x.f = f;
  uint32_t r = x.u + 0x7FFFu + ((x.u >> 16) & 1u);   // RNE
  return r >> 16;
}
__device__ __forceinline__ float blo(uint32_t p){ union{uint32_t u;float f;}x; x.u=p<<16;         return x.f; }
__device__ __forceinline__ float bhi(uint32_t p){ union{uint32_t u;float f;}x; x.u=p&0xFFFF0000u; return x.f; }

// ---------- fused prep: weight transpose+cast, x->h0 bf16, per-block edge list ----------
#define TB 152           // 80 (W1) + 64 (W2a) + 8 (W2l) 64x64 transpose tiles
#define XB (MPAD/4)      // 5024
#define EB ((NE+255)/256)
__global__ __launch_bounds__(256) void prep_all(
    const float* __restrict__ x, const int* __restrict__ src, const int* __restrict__ dst,
    const float* __restrict__ W1, const float* __restrict__ W2a, const float* __restrict__ W2l,
    u16* __restrict__ W1t, u16* __restrict__ W2at, u16* __restrict__ W2lt,
    u16* __restrict__ h0, int* __restrict__ bcnt, uint32_t* __restrict__ belist)
{
  __shared__ u16 Ts[64][65];
  int b = blockIdx.x, tid = threadIdx.x;
  if (b < TB){
    const float* srcp; u16* dstp; int ldS, k0, n0;
    if (b < 80){
      int layer = b >> 4, sub = b & 15;
      srcp = W1 + layer*65536; dstp = W1t + layer*65536; ldS = 256;
      k0 = (sub >> 2)*64; n0 = (sub & 3)*64;
    } else if (b < 144){
      int bb = b - 80; int layer = bb >> 4, sub = bb & 15;
      srcp = W2a + layer*65536; dstp = W2at + layer*65536; ldS = 256;
      k0 = (sub >> 2)*64; n0 = (sub & 3)*64;
    } else {
      int sub = b - 144;
      srcp = W2l; dstp = W2lt; ldS = 128;
      k0 = (sub >> 1)*64; n0 = (sub & 1)*64;
    }
    int c = tid & 63, r0 = tid >> 6;
    #pragma unroll
    for (int i = 0; i < 16; ++i){
      int r = r0 + i*4;
      Ts[r][c] = (u16)f2b(srcp[(size_t)(k0 + r)*ldS + n0 + c]);
    }
    __syncthreads();
    #pragma unroll
    for (int i = 0; i < 16; ++i){
      int n = r0 + i*4;
      dstp[(size_t)(n0 + n)*256 + k0 + c] = Ts[c][n];
    }
  } else if (b < TB + XB){
    int bb = b - TB;
    int row  = bb*4 + (tid >> 6);
    int lane = tid & 63;
    uint2 o = make_uint2(0u, 0u);
    if (row < NN){
      float4 f = *(const float4*)(x + (size_t)row*DD + lane*4);
      o.x = f2b(f.x) | (f2b(f.y) << 16);
      o.y = f2b(f.z) | (f2b(f.w) << 16);
    }
    *(uint2*)(h0 + (size_t)row*DD + lane*4) = o;
  } else {
    int e = (b - TB - XB)*256 + tid;
    if (e < NE){
      int d = dst[e];
      int blk = d >> 5;
      int slot = atomicAdd(&bcnt[blk], 1);
      if (slot < BCAP)
        belist[(size_t)blk*BCAP + slot] = (uint32_t)src[e] | ((uint32_t)(d & 31) << 16);
    }
  }
}

// ---------- fused layer ----------
__global__ __launch_bounds__(256, 3) void gin_fused(
    const u16* __restrict__ hin, const int* __restrict__ bcnt,
    const uint32_t* __restrict__ belist,
    const float* __restrict__ eps_arr, int layer,
    const u16* __restrict__ w1, const float* __restrict__ b1,
    const u16* __restrict__ w2, const float* __restrict__ b2,
    const float* __restrict__ gma, const float* __restrict__ bta,
    const float* __restrict__ mu,  const float* __restrict__ var,
    u16* __restrict__ hout, float* __restrict__ outf, int last)
{
  __shared__ __align__(16) float zf[32*RSF];  // f32 accumulator z (33.0 KB)
  __shared__ __align__(16) u16 As[8*SS];      // bf16 z -> t -> epilogue staging (20.6 KB)
  int tid  = threadIdx.x;
  int lane = tid & 63, w = tid >> 6;
  int m0 = blockIdx.x * 32;
  int l15 = lane & 15, l4 = lane >> 4;

  // ---- phase 0a: seed zf = (1+eps)*h[v] ----
  {
    float e = 1.0f + eps_arr[layer];
    #pragma unroll
    for (int i = 0; i < 8; ++i){
      int r = w*8 + i;
      int v = m0 + r;
      float4 s4 = {0.f, 0.f, 0.f, 0.f};
      if (v < NN){
        uint2 ov = *(const uint2*)(hin + (size_t)v*DD + lane*4);
        s4.x = e*blo(ov.x); s4.y = e*bhi(ov.x);
        s4.z = e*blo(ov.y); s4.w = e*bhi(ov.y);
      }
      *(float4*)(zf + r*RSF + lane*4) = s4;
    }
  }
  __syncthreads();

  // ---- phase 0b: streamed edge accumulate ----
  // EVERY wave iterates ALL edges; wave w owns dims [64w, 64w+64), lane owns 1 dim.
  {
    const uint32_t* bl = belist + (size_t)blockIdx.x * BCAP;
    int E = bcnt[blockIdx.x]; E = E > BCAP ? BCAP : E;
    const u16* hd  = hin + w*64 + lane;     // this wave-lane's dim column
    float*     zc  = zf  + w*64 + lane;
    for (int base = 0; base < E; base += 32){
      int nv = E - base; nv = nv > 32 ? 32 : nv;        // uniform
      uint32_t pk[32]; u16 hv[32];
      #pragma unroll
      for (int c = 0; c < 32; ++c)
        pk[c] = (c < nv) ? bl[base + c] : 0x80000000u;  // sentinel: src=0, dl=0, flag
      #pragma unroll
      for (int c = 0; c < 32; ++c)
        hv[c] = hd[(size_t)(pk[c] & 0xFFFFu) * DD];     // 32 x 128B coalesced, in flight
      #pragma unroll
      for (int c = 0; c < 32; ++c){
        float f = (pk[c] & 0x80000000u) ? 0.0f : blo((uint32_t)hv[c]);
        atomicAdd(zc + ((pk[c] >> 16) & 31)*RSF, f);    // ds_add_f32, wave-uniform row
      }
    }
  }
  __syncthreads();

  // ---- phase 0c: convert zf -> As (bf16, MFMA-B slice layout) ----
  {
    #pragma unroll
    for (int i = 0; i < 8; ++i){
      int r = w*8 + i;
      float4 s4 = *(const float4*)(zf + r*RSF + lane*4);
      uint2 o;
      o.x = f2b(s4.x) | (f2b(s4.y) << 16);
      o.y = f2b(s4.z) | (f2b(s4.w) << 16);
      *(uint2*)(As + (lane >> 3)*SS + r*RS + (lane & 7)*4) = o;
    }
  }
  __syncthreads();

  // ---- phase 1: GEMM1^T: t^T[hid][zrow] = sum_k W1t[hid][k] * z[zrow][k] ----
  f32x4 acc1[4][2];
  #pragma unroll
  for (int i=0;i<4;++i)
    #pragma unroll
    for (int j=0;j<2;++j){ f32x4 zr={0.f,0.f,0.f,0.f}; acc1[i][j]=zr; }
  {
    int hidb = w*64;
    for (int s = 0; s < 8; ++s){
      bf16x8 af[4], bz[2];
      #pragma unroll
      for (int mi=0;mi<4;++mi)
        af[mi] = *(const bf16x8*)(w1 + (size_t)(hidb + mi*16 + l15)*DD + s*32 + l4*8);
      #pragma unroll
      for (int nj=0;nj<2;++nj)
        bz[nj] = *(const bf16x8*)(As + s*SS + (nj*16 + l15)*RS + l4*8);
      #pragma unroll
      for (int mi=0;mi<4;++mi)
        #pragma unroll
        for (int nj=0;nj<2;++nj)
          acc1[mi][nj] = __builtin_amdgcn_mfma_f32_16x16x32_bf16(af[mi], bz[nj], acc1[mi][nj], 0,0,0);
    }
  }
  __syncthreads();   // all z reads done -> reuse As for t

  // ---- phase 2: t = relu(t + b1) -> As in A-operand layout ----
  {
    int hidb = w*64;
    #pragma unroll
    for (int mi=0;mi<4;++mi){
      float4 bv = *(const float4*)(b1 + hidb + mi*16 + l4*4);
      int s2 = w*2 + (mi >> 1);
      int kp = (mi & 1)*16 + l4*4;
      #pragma unroll
      for (int nj=0;nj<2;++nj){
        int zrow = nj*16 + l15;
        float v0 = acc1[mi][nj][0] + bv.x; v0 = v0 > 0.f ? v0 : 0.f;
        float v1 = acc1[mi][nj][1] + bv.y; v1 = v1 > 0.f ? v1 : 0.f;
        float v2 = acc1[mi][nj][2] + bv.z; v2 = v2 > 0.f ? v2 : 0.f;
        float v3 = acc1[mi][nj][3] + bv.w; v3 = v3 > 0.f ? v3 : 0.f;
        uint2 pk;
        pk.x = f2b(v0) | (f2b(v1) << 16);
        pk.y = f2b(v2) | (f2b(v3) << 16);
        *(uint2*)(As + s2*SS + zrow*RS + kp) = pk;
      }
    }
  }
  __syncthreads();

  // ---- phase 3: GEMM2 + epilogue ----
  if (!last){
    f32x4 acc2[2][4];
    #pragma unroll
    for (int i=0;i<2;++i)
      #pragma unroll
      for (int j=0;j<4;++j){ f32x4 zr={0.f,0.f,0.f,0.f}; acc2[i][j]=zr; }
    int cb = w*64;
    for (int s = 0; s < 8; ++s){
      bf16x8 at[2], bw[4];
      #pragma unroll
      for (int i=0;i<2;++i)
        at[i] = *(const bf16x8*)(As + s*SS + (i*16 + l15)*RS + l4*8);
      #pragma unroll
      for (int j=0;j<4;++j)
        bw[j] = *(const bf16x8*)(w2 + (size_t)(cb + j*16 + l15)*DD + s*32 + l4*8);
      #pragma unroll
      for (int i=0;i<2;++i)
        #pragma unroll
        for (int j=0;j<4;++j)
          acc2[i][j] = __builtin_amdgcn_mfma_f32_16x16x32_bf16(at[i], bw[j], acc2[i][j], 0,0,0);
    }
    __syncthreads();                       // done reading t; reuse As for staging
    u16* St = As;                          // 32 x 256, stride STS=264
    #pragma unroll
    for (int j=0;j<4;++j){
      int col = cb + j*16 + l15;
      float sc = rsqrtf(var[col] + 1e-5f) * gma[col];
      float sh = (b2[col] - mu[col]) * sc + bta[col];
      #pragma unroll
      for (int i=0;i<2;++i){
        #pragma unroll
        for (int r=0;r<4;++r){
          int row = i*16 + l4*4 + r;
          float vv = acc2[i][j][r]*sc + sh;
          vv = vv > 0.f ? vv : 0.f;
          St[row*STS + col] = (u16)f2b(vv);
        }
      }
    }
    __syncthreads();
    #pragma unroll
    for (int it = 0; it < 4; ++it){
      int idx = it*256 + tid;              // 1024 uint4 = 32 rows x 32 chunks
      int row = idx >> 5, c = idx & 31;
      *(uint4*)(hout + (size_t)(m0 + row)*DD + c*8) = *(const uint4*)(St + row*STS + c*8);
    }
  } else {
    f32x4 acc2[2][2];
    #pragma unroll
    for (int i=0;i<2;++i)
      #pragma unroll
      for (int j=0;j<2;++j){ f32x4 zr={0.f,0.f,0.f,0.f}; acc2[i][j]=zr; }
    int cbk = w*32;
    for (int s = 0; s < 8; ++s){
      bf16x8 at[2], bw[2];
      #pragma unroll
      for (int i=0;i<2;++i)
        at[i] = *(const bf16x8*)(As + s*SS + (i*16 + l15)*RS + l4*8);
      #pragma unroll
      for (int j=0;j<2;++j)
        bw[j] = *(const bf16x8*)(w2 + (size_t)(cbk + j*16 + l15)*DD + s*32 + l4*8);
      #pragma unroll
      for (int i=0;i<2;++i)
        #pragma unroll
        for (int j=0;j<2;++j)
          acc2[i][j] = __builtin_amdgcn_mfma_f32_16x16x32_bf16(at[i], bw[j], acc2[i][j], 0,0,0);
    }
    __syncthreads();
    float* Sf = (float*)As;                // 32 x 128, stride SFS=132
    #pragma unroll
    for (int j=0;j<2;++j){
      int col = cbk + j*16 + l15;
      float sh = b2[col];
      #pragma unroll
      for (int i=0;i<2;++i){
        #pragma unroll
        for (int r=0;r<4;++r){
          int row = i*16 + l4*4 + r;
          Sf[row*SFS + col] = acc2[i][j][r] + sh;
        }
      }
    }
    __syncthreads();
    #pragma unroll
    for (int it = 0; it < 4; ++it){
      int idx = it*256 + tid;              // 1024 uint4 = 32 rows x 32 chunks
      int row = idx >> 5, c = idx & 31;
      if (m0 + row < NN)
        *(uint4*)(outf + (size_t)(m0 + row)*DOUT + c*4) = *(const uint4*)(Sf + row*SFS + c*4);
    }
  }
}

extern "C" void kernel_launch(void* const* d_in, const int* in_sizes, int n_in,
                              void* d_out, int out_size, void* d_ws, size_t ws_size,
                              hipStream_t stream)
{
  const float* x     = (const float*)d_in[0];
  const int*   ei    = (const int*)  d_in[1];
  const float* W1    = (const float*)d_in[2];
  const float* b1    = (const float*)d_in[3];
  const float* W2a   = (const float*)d_in[4];
  const float* b2a   = (const float*)d_in[5];
  const float* W2l   = (const float*)d_in[6];
  const float* b2l   = (const float*)d_in[7];
  const float* eps   = (const float*)d_in[8];
  const float* gma   = (const float*)d_in[9];
  const float* bta   = (const float*)d_in[10];
  const float* mu    = (const float*)d_in[11];
  const float* var   = (const float*)d_in[12];
  float* out = (float*)d_out;

  char* ws = (char*)d_ws;
  size_t off = 0;
  auto alloc = [&](size_t bytes)->void*{
    void* p = ws + off; off += (bytes + 255) & ~(size_t)255; return p;
  };
  u16*      h0     = (u16*)alloc((size_t)MPAD*DD*2);
  u16*      h1     = (u16*)alloc((size_t)MPAD*DD*2);
  int*      bcnt   = (int*)alloc((size_t)NBLK*4);
  uint32_t* belist = (uint32_t*)alloc((size_t)NBLK*BCAP*4);
  u16*      W1t    = (u16*)alloc((size_t)5*65536*2);
  u16*      W2at   = (u16*)alloc((size_t)4*65536*2);
  u16*      W2lt   = (u16*)alloc((size_t)32768*2);

  const int* srcA = ei;
  const int* dstA = ei + NE;

  hipMemsetAsync(bcnt, 0, (size_t)NBLK*4, stream);
  prep_all<<<TB + XB + EB, 256, 0, stream>>>(x, srcA, dstA, W1, W2a, W2l,
                                             W1t, W2at, W2lt, h0, bcnt, belist);

  u16* hbuf[2] = { h0, h1 };
  for (int L = 0; L < 5; ++L){
    const u16* hin = hbuf[L & 1];
    u16*       ho  = hbuf[1 - (L & 1)];
    if (L < 4){
      gin_fused<<<MPAD/32, 256, 0, stream>>>(hin, bcnt, belist, eps, L,
          W1t + (size_t)L*65536, b1 + L*256,
          W2at + (size_t)L*65536, b2a + L*256,
          gma + L*256, bta + L*256, mu + L*256, var + L*256,
          ho, nullptr, 0);
    } else {
      gin_fused<<<MPAD/32, 256, 0, stream>>>(hin, bcnt, belist, eps, L,
          W1t + (size_t)L*65536, b1 + L*256,
          W2lt, b2l,
          nullptr, nullptr, nullptr, nullptr,
          nullptr, out, 1);
    }
  }
}

// Round 10
// 330.009 us; speedup vs baseline: 9.0632x; 9.0632x over previous
//
#include <hip/hip_runtime.h>
#include <stdint.h>

// Fused GIN layer: gather (full-row uint4 pairs, bpermute reduce) -> LDS z ->
// GEMM1^T -> t(LDS) -> GEMM2 -> LDS-staged coalesced epilogue.
// 628 blocks x 4 waves, 32-row tiles.
#define NN    20000
#define NE    320000
#define MPAD  20096      // 628 * 32
#define DD    256
#define DOUT  128
#define CAP   64
#define RS    40         // As row stride (elems) within a 32-K slice
#define SS    1288       // As slice stride: 32*40 + 8 pad
#define STS   264        // epilogue u16 staging row stride
#define SFS   132        // epilogue f32 staging row stride

typedef unsigned short u16;
typedef __attribute__((ext_vector_type(8))) __bf16 bf16x8;
typedef __attribute__((ext_vector_type(4))) float  f32x4;

__device__ __forceinline__ uint32_t f2b(float f){
  union { float f; uint32_t u; } x; x.f = f;
  uint32_t r = x.u + 0x7FFFu + ((x.u >> 16) & 1u);   // RNE
  return r >> 16;
}
__device__ __forceinline__ float blo(uint32_t p){ union{uint32_t u;float f;}x; x.u=p<<16;         return x.f; }
__device__ __forceinline__ float bhi(uint32_t p){ union{uint32_t u;float f;}x; x.u=p&0xFFFF0000u; return x.f; }
__device__ __forceinline__ int   fiu(float f){ union{float f;int i;}x; x.f=f; return x.i; }
__device__ __forceinline__ float uif(int i){ union{int i;float f;}x; x.i=i; return x.f; }

// ---------- fused prep: LDS-tiled weight transpose+cast, x->h0 bf16, CSR fill ----------
#define TB 152           // 80 (W1) + 64 (W2a) + 8 (W2l) 64x64 transpose tiles
#define XB (MPAD/4)      // 5024
#define EB ((NE+255)/256)
__global__ __launch_bounds__(256) void prep_all(
    const float* __restrict__ x, const int* __restrict__ src, const int* __restrict__ dst,
    const float* __restrict__ W1, const float* __restrict__ W2a, const float* __restrict__ W2l,
    u16* __restrict__ W1t, u16* __restrict__ W2at, u16* __restrict__ W2lt,
    u16* __restrict__ h0, int* __restrict__ cnt, int* __restrict__ csr)
{
  __shared__ u16 Ts[64][65];
  int b = blockIdx.x, tid = threadIdx.x;
  if (b < TB){
    const float* srcp; u16* dstp; int ldS, k0, n0;
    if (b < 80){
      int layer = b >> 4, sub = b & 15;
      srcp = W1 + layer*65536; dstp = W1t + layer*65536; ldS = 256;
      k0 = (sub >> 2)*64; n0 = (sub & 3)*64;
    } else if (b < 144){
      int bb = b - 80; int layer = bb >> 4, sub = bb & 15;
      srcp = W2a + layer*65536; dstp = W2at + layer*65536; ldS = 256;
      k0 = (sub >> 2)*64; n0 = (sub & 3)*64;
    } else {
      int sub = b - 144;
      srcp = W2l; dstp = W2lt; ldS = 128;
      k0 = (sub >> 1)*64; n0 = (sub & 1)*64;
    }
    int c = tid & 63, r0 = tid >> 6;
    #pragma unroll
    for (int i = 0; i < 16; ++i){
      int r = r0 + i*4;
      Ts[r][c] = (u16)f2b(srcp[(size_t)(k0 + r)*ldS + n0 + c]);
    }
    __syncthreads();
    #pragma unroll
    for (int i = 0; i < 16; ++i){
      int n = r0 + i*4;
      dstp[(size_t)(n0 + n)*256 + k0 + c] = Ts[c][n];
    }
  } else if (b < TB + XB){
    int bb = b - TB;
    int row  = bb*4 + (tid >> 6);
    int lane = tid & 63;
    uint2 o = make_uint2(0u, 0u);
    if (row < NN){
      float4 f = *(const float4*)(x + (size_t)row*DD + lane*4);
      o.x = f2b(f.x) | (f2b(f.y) << 16);
      o.y = f2b(f.z) | (f2b(f.w) << 16);
    }
    *(uint2*)(h0 + (size_t)row*DD + lane*4) = o;
  } else {
    int e = (b - TB - XB)*256 + tid;
    if (e < NE){
      int d = dst[e];
      int slot = atomicAdd(&cnt[d], 1);
      if (slot < CAP) csr[d*CAP + slot] = src[e];
    }
  }
}

// ---------- fused layer ----------
__global__ __launch_bounds__(256, 3) void gin_fused(
    const u16* __restrict__ hin, const int* __restrict__ cnt, const int* __restrict__ csr,
    const float* __restrict__ eps_arr, int layer,
    const u16* __restrict__ w1, const float* __restrict__ b1,
    const u16* __restrict__ w2, const float* __restrict__ b2,
    const float* __restrict__ gma, const float* __restrict__ bta,
    const float* __restrict__ mu,  const float* __restrict__ var,
    u16* __restrict__ hout, float* __restrict__ outf, int last)
{
  __shared__ __align__(16) u16 As[8*SS];      // z slices -> t slices -> epilogue staging
  int tid  = threadIdx.x;
  int lane = tid & 63, w = tid >> 6;
  int m0 = blockIdx.x * 32;
  int l15 = lane & 15, l4 = lane >> 4;

  // ---- phase 0: gather z = (1+eps)*h[v] + sum_nb h[u] -> As (B-slice layout) ----
  // half=lane>>5 picks edge parity; kl=lane&31 owns 16B chunk (8 dims) of the row.
  // One uint4 load instruction = 2 full 512B neighbor rows. 8 loads (16 edges) in flight.
  {
    float e = 1.0f + eps_arr[layer];
    int half = lane >> 5, kl = lane & 31;
    int xi = (lane ^ 32) << 2;                    // bpermute byte index
    const u16* hrow = hin + kl*8;
    u16* dstL = As + (kl >> 2)*SS + (kl & 3)*8;
    for (int i = 0; i < 8; ++i){
      int row = w*8 + i;
      int v = __builtin_amdgcn_readfirstlane(m0 + row);
      float a0=0.f,a1=0.f,a2=0.f,a3=0.f,a4=0.f,a5=0.f,a6=0.f,a7=0.f;
      if (v < NN){
        uint4 ov = *(const uint4*)(hrow + (size_t)v*DD);
        int deg = cnt[v]; deg = deg > CAP ? CAP : deg;
        const int* lst = csr + (size_t)v*CAP;
        for (int base = 0; base < deg; base += 16){
          int4 q[4];
          #pragma unroll
          for (int c = 0; c < 4; ++c) q[c] = *(const int4*)(lst + base + 4*c);  // s_load
          int idv[8];
          #pragma unroll
          for (int c = 0; c < 4; ++c){
            idv[2*c]   = half ? q[c].y : q[c].x;
            idv[2*c+1] = half ? q[c].w : q[c].z;
          }
          uint4 rv[8];
          #pragma unroll
          for (int c = 0; c < 8; ++c){
            int g = (base + 2*c + half < deg) ? idv[c] : v;   // safe addr
            rv[c] = *(const uint4*)(hrow + (size_t)g*DD);     // 2 rows / instr, 8 in flight
          }
          #pragma unroll
          for (int c = 0; c < 8; ++c){
            if (base + 2*c + half < deg){
              a0 += blo(rv[c].x); a1 += bhi(rv[c].x);
              a2 += blo(rv[c].y); a3 += bhi(rv[c].y);
              a4 += blo(rv[c].z); a5 += bhi(rv[c].z);
              a6 += blo(rv[c].w); a7 += bhi(rv[c].w);
            }
          }
        }
        float eh = half ? 0.0f : e;               // own-term added once (half 0)
        a0 += eh*blo(ov.x); a1 += eh*bhi(ov.x);
        a2 += eh*blo(ov.y); a3 += eh*bhi(ov.y);
        a4 += eh*blo(ov.z); a5 += eh*bhi(ov.z);
        a6 += eh*blo(ov.w); a7 += eh*bhi(ov.w);
      }
      // cross-half reduce (register-only permute; all 64 lanes execute)
      a0 += uif(__builtin_amdgcn_ds_bpermute(xi, fiu(a0)));
      a1 += uif(__builtin_amdgcn_ds_bpermute(xi, fiu(a1)));
      a2 += uif(__builtin_amdgcn_ds_bpermute(xi, fiu(a2)));
      a3 += uif(__builtin_amdgcn_ds_bpermute(xi, fiu(a3)));
      a4 += uif(__builtin_amdgcn_ds_bpermute(xi, fiu(a4)));
      a5 += uif(__builtin_amdgcn_ds_bpermute(xi, fiu(a5)));
      a6 += uif(__builtin_amdgcn_ds_bpermute(xi, fiu(a6)));
      a7 += uif(__builtin_amdgcn_ds_bpermute(xi, fiu(a7)));
      if (half == 0){
        uint4 o;
        o.x = f2b(a0) | (f2b(a1) << 16);
        o.y = f2b(a2) | (f2b(a3) << 16);
        o.z = f2b(a4) | (f2b(a5) << 16);
        o.w = f2b(a6) | (f2b(a7) << 16);
        *(uint4*)(dstL + row*RS) = o;
      }
    }
  }
  __syncthreads();

  // ---- phase 1: GEMM1^T: t^T[hid][zrow] = sum_k W1t[hid][k] * z[zrow][k] ----
  f32x4 acc1[4][2];
  #pragma unroll
  for (int i=0;i<4;++i)
    #pragma unroll
    for (int j=0;j<2;++j){ f32x4 zr={0.f,0.f,0.f,0.f}; acc1[i][j]=zr; }
  {
    int hidb = w*64;
    for (int s = 0; s < 8; ++s){
      bf16x8 af[4], bz[2];
      #pragma unroll
      for (int mi=0;mi<4;++mi)
        af[mi] = *(const bf16x8*)(w1 + (size_t)(hidb + mi*16 + l15)*DD + s*32 + l4*8);
      #pragma unroll
      for (int nj=0;nj<2;++nj)
        bz[nj] = *(const bf16x8*)(As + s*SS + (nj*16 + l15)*RS + l4*8);
      #pragma unroll
      for (int mi=0;mi<4;++mi)
        #pragma unroll
        for (int nj=0;nj<2;++nj)
          acc1[mi][nj] = __builtin_amdgcn_mfma_f32_16x16x32_bf16(af[mi], bz[nj], acc1[mi][nj], 0,0,0);
    }
  }
  __syncthreads();   // all z reads done -> reuse As for t

  // ---- phase 2: t = relu(t + b1) -> As in A-operand layout ----
  {
    int hidb = w*64;
    #pragma unroll
    for (int mi=0;mi<4;++mi){
      float4 bv = *(const float4*)(b1 + hidb + mi*16 + l4*4);
      int s2 = w*2 + (mi >> 1);
      int kp = (mi & 1)*16 + l4*4;
      #pragma unroll
      for (int nj=0;nj<2;++nj){
        int zrow = nj*16 + l15;
        float v0 = acc1[mi][nj][0] + bv.x; v0 = v0 > 0.f ? v0 : 0.f;
        float v1 = acc1[mi][nj][1] + bv.y; v1 = v1 > 0.f ? v1 : 0.f;
        float v2 = acc1[mi][nj][2] + bv.z; v2 = v2 > 0.f ? v2 : 0.f;
        float v3 = acc1[mi][nj][3] + bv.w; v3 = v3 > 0.f ? v3 : 0.f;
        uint2 pk;
        pk.x = f2b(v0) | (f2b(v1) << 16);
        pk.y = f2b(v2) | (f2b(v3) << 16);
        *(uint2*)(As + s2*SS + zrow*RS + kp) = pk;
      }
    }
  }
  __syncthreads();

  // ---- phase 3: GEMM2 + epilogue ----
  if (!last){
    f32x4 acc2[2][4];
    #pragma unroll
    for (int i=0;i<2;++i)
      #pragma unroll
      for (int j=0;j<4;++j){ f32x4 zr={0.f,0.f,0.f,0.f}; acc2[i][j]=zr; }
    int cb = w*64;
    for (int s = 0; s < 8; ++s){
      bf16x8 at[2], bw[4];
      #pragma unroll
      for (int i=0;i<2;++i)
        at[i] = *(const bf16x8*)(As + s*SS + (i*16 + l15)*RS + l4*8);
      #pragma unroll
      for (int j=0;j<4;++j)
        bw[j] = *(const bf16x8*)(w2 + (size_t)(cb + j*16 + l15)*DD + s*32 + l4*8);
      #pragma unroll
      for (int i=0;i<2;++i)
        #pragma unroll
        for (int j=0;j<4;++j)
          acc2[i][j] = __builtin_amdgcn_mfma_f32_16x16x32_bf16(at[i], bw[j], acc2[i][j], 0,0,0);
    }
    __syncthreads();                       // done reading t; reuse As for staging
    u16* St = As;                          // 32 x 256, stride STS=264
    #pragma unroll
    for (int j=0;j<4;++j){
      int col = cb + j*16 + l15;
      float sc = rsqrtf(var[col] + 1e-5f) * gma[col];
      float sh = (b2[col] - mu[col]) * sc + bta[col];
      #pragma unroll
      for (int i=0;i<2;++i){
        #pragma unroll
        for (int r=0;r<4;++r){
          int row = i*16 + l4*4 + r;
          float vv = acc2[i][j][r]*sc + sh;
          vv = vv > 0.f ? vv : 0.f;
          St[row*STS + col] = (u16)f2b(vv);
        }
      }
    }
    __syncthreads();
    #pragma unroll
    for (int it = 0; it < 4; ++it){
      int idx = it*256 + tid;              // 1024 uint4 = 32 rows x 32 chunks
      int row = idx >> 5, c = idx & 31;
      *(uint4*)(hout + (size_t)(m0 + row)*DD + c*8) = *(const uint4*)(St + row*STS + c*8);
    }
  } else {
    f32x4 acc2[2][2];
    #pragma unroll
    for (int i=0;i<2;++i)
      #pragma unroll
      for (int j=0;j<2;++j){ f32x4 zr={0.f,0.f,0.f,0.f}; acc2[i][j]=zr; }
    int cbk = w*32;
    for (int s = 0; s < 8; ++s){
      bf16x8 at[2], bw[2];
      #pragma unroll
      for (int i=0;i<2;++i)
        at[i] = *(const bf16x8*)(As + s*SS + (i*16 + l15)*RS + l4*8);
      #pragma unroll
      for (int j=0;j<2;++j)
        bw[j] = *(const bf16x8*)(w2 + (size_t)(cbk + j*16 + l15)*DD + s*32 + l4*8);
      #pragma unroll
      for (int i=0;i<2;++i)
        #pragma unroll
        for (int j=0;j<2;++j)
          acc2[i][j] = __builtin_amdgcn_mfma_f32_16x16x32_bf16(at[i], bw[j], acc2[i][j], 0,0,0);
    }
    __syncthreads();
    float* Sf = (float*)As;                // 32 x 128, stride SFS=132
    #pragma unroll
    for (int j=0;j<2;++j){
      int col = cbk + j*16 + l15;
      float sh = b2[col];
      #pragma unroll
      for (int i=0;i<2;++i){
        #pragma unroll
        for (int r=0;r<4;++r){
          int row = i*16 + l4*4 + r;
          Sf[row*SFS + col] = acc2[i][j][r] + sh;
        }
      }
    }
    __syncthreads();
    #pragma unroll
    for (int it = 0; it < 4; ++it){
      int idx = it*256 + tid;              // 1024 uint4 = 32 rows x 32 chunks
      int row = idx >> 5, c = idx & 31;
      if (m0 + row < NN)
        *(uint4*)(outf + (size_t)(m0 + row)*DOUT + c*4) = *(const uint4*)(Sf + row*SFS + c*4);
    }
  }
}

extern "C" void kernel_launch(void* const* d_in, const int* in_sizes, int n_in,
                              void* d_out, int out_size, void* d_ws, size_t ws_size,
                              hipStream_t stream)
{
  const float* x     = (const float*)d_in[0];
  const int*   ei    = (const int*)  d_in[1];
  const float* W1    = (const float*)d_in[2];
  const float* b1    = (const float*)d_in[3];
  const float* W2a   = (const float*)d_in[4];
  const float* b2a   = (const float*)d_in[5];
  const float* W2l   = (const float*)d_in[6];
  const float* b2l   = (const float*)d_in[7];
  const float* eps   = (const float*)d_in[8];
  const float* gma   = (const float*)d_in[9];
  const float* bta   = (const float*)d_in[10];
  const float* mu    = (const float*)d_in[11];
  const float* var   = (const float*)d_in[12];
  float* out = (float*)d_out;

  char* ws = (char*)d_ws;
  size_t off = 0;
  auto alloc = [&](size_t bytes)->void*{
    void* p = ws + off; off += (bytes + 255) & ~(size_t)255; return p;
  };
  u16* h0   = (u16*)alloc((size_t)MPAD*DD*2);
  u16* h1   = (u16*)alloc((size_t)MPAD*DD*2);
  int* cnt  = (int*)alloc((size_t)NN*4);
  int* csr  = (int*)alloc((size_t)NN*CAP*4 + 64);
  u16* W1t  = (u16*)alloc((size_t)5*65536*2);
  u16* W2at = (u16*)alloc((size_t)4*65536*2);
  u16* W2lt = (u16*)alloc((size_t)32768*2);

  const int* srcA = ei;
  const int* dstA = ei + NE;

  hipMemsetAsync(cnt, 0, (size_t)NN*4, stream);
  prep_all<<<TB + XB + EB, 256, 0, stream>>>(x, srcA, dstA, W1, W2a, W2l,
                                             W1t, W2at, W2lt, h0, cnt, csr);

  u16* hbuf[2] = { h0, h1 };
  for (int L = 0; L < 5; ++L){
    const u16* hin = hbuf[L & 1];
    u16*       ho  = hbuf[1 - (L & 1)];
    if (L < 4){
      gin_fused<<<MPAD/32, 256, 0, stream>>>(hin, cnt, csr, eps, L,
          W1t + (size_t)L*65536, b1 + L*256,
          W2at + (size_t)L*65536, b2a + L*256,
          gma + L*256, bta + L*256, mu + L*256, var + L*256,
          ho, nullptr, 0);
    } else {
      gin_fused<<<MPAD/32, 256, 0, stream>>>(hin, cnt, csr, eps, L,
          W1t + (size_t)L*65536, b1 + L*256,
          W2lt, b2l,
          nullptr, nullptr, nullptr, nullptr,
          nullptr, out, 1);
    }
  }
}